// Round 1
// baseline (437.893 us; speedup 1.0000x reference)
//
#include <hip/hip_runtime.h>

// 4-level Haar DWT + IDWT round-trip. Every aligned 16-element block on the
// last axis (4096 % 16 == 0) is independent: one thread = one block of 16.
// Exact same fp32 op sequence as the JAX reference (no reassociation).

#define WBLK 16  // 2^LEVEL

__global__ __launch_bounds__(256) void wavelet_rt_kernel(
    const float4* __restrict__ in, float4* __restrict__ out, int nthreads) {
  int t = blockIdx.x * blockDim.x + threadIdx.x;
  if (t >= nthreads) return;

  const float S = 0.7071067811865476f;  // fp32(1/sqrt(2)), same as reference

  // Load 16 contiguous floats (one 64B line per lane).
  float v[16];
  #pragma unroll
  for (int k = 0; k < 4; ++k) {
    float4 r = in[t * 4 + k];
    v[4 * k + 0] = r.x; v[4 * k + 1] = r.y;
    v[4 * k + 2] = r.z; v[4 * k + 3] = r.w;
  }

  // ---- Analysis (4 levels) ----
  float a1[8], d1[8];
  #pragma unroll
  for (int i = 0; i < 8; ++i) {
    float e = v[2 * i], o = v[2 * i + 1];
    a1[i] = (e + o) * S;
    d1[i] = (e - o) * S;
  }
  float a2[4], d2[4];
  #pragma unroll
  for (int i = 0; i < 4; ++i) {
    float e = a1[2 * i], o = a1[2 * i + 1];
    a2[i] = (e + o) * S;
    d2[i] = (e - o) * S;
  }
  float a3[2], d3[2];
  #pragma unroll
  for (int i = 0; i < 2; ++i) {
    float e = a2[2 * i], o = a2[2 * i + 1];
    a3[i] = (e + o) * S;
    d3[i] = (e - o) * S;
  }
  float a4 = (a3[0] + a3[1]) * S;
  float d4 = (a3[0] - a3[1]) * S;

  // ---- Synthesis (4 levels) ----
  float b3[2];
  b3[0] = (a4 + d4) * S;
  b3[1] = (a4 - d4) * S;
  float b2[4];
  #pragma unroll
  for (int i = 0; i < 2; ++i) {
    b2[2 * i + 0] = (b3[i] + d3[i]) * S;
    b2[2 * i + 1] = (b3[i] - d3[i]) * S;
  }
  float b1[8];
  #pragma unroll
  for (int i = 0; i < 4; ++i) {
    b1[2 * i + 0] = (b2[i] + d2[i]) * S;
    b1[2 * i + 1] = (b2[i] - d2[i]) * S;
  }
  float w[16];
  #pragma unroll
  for (int i = 0; i < 8; ++i) {
    w[2 * i + 0] = (b1[i] + d1[i]) * S;
    w[2 * i + 1] = (b1[i] - d1[i]) * S;
  }

  // Store 16 contiguous floats.
  #pragma unroll
  for (int k = 0; k < 4; ++k) {
    float4 o4;
    o4.x = w[4 * k + 0]; o4.y = w[4 * k + 1];
    o4.z = w[4 * k + 2]; o4.w = w[4 * k + 3];
    out[t * 4 + k] = o4;
  }
}

extern "C" void kernel_launch(void* const* d_in, const int* in_sizes, int n_in,
                              void* d_out, int out_size, void* d_ws, size_t ws_size,
                              hipStream_t stream) {
  const float* x = (const float*)d_in[0];
  float* out = (float*)d_out;
  int nthreads = out_size / WBLK;  // 67,108,864 / 16 = 4,194,304
  int block = 256;
  int grid = (nthreads + block - 1) / block;  // 16384 workgroups
  wavelet_rt_kernel<<<grid, block, 0, stream>>>(
      (const float4*)x, (float4*)out, nthreads);
}

// Round 2
// 409.221 us; speedup vs baseline: 1.0701x; 1.0701x over previous
//
#include <hip/hip_runtime.h>

// 4-level Haar DWT + IDWT round-trip, (32*512*4096) fp32.
// Decomposition: one thread owns 4 contiguous floats (one dwordx4, perfectly
// coalesced). Levels 1-2 are lane-local; levels 3-4 butterfly across lane
// pairs (xor 1) and lane quads (xor 2) via __shfl_xor, with both lanes of a
// pair computing the duplicated coarse/detail coefficients. Synthesis is then
// fully lane-local (coarse values are duplicated, details are lane-local).
// Same fp32 op sequence as the JAX reference.

__global__ __launch_bounds__(256) void wavelet_rt_kernel(
    const float4* __restrict__ in, float4* __restrict__ out, int nthreads) {
  int t = blockIdx.x * blockDim.x + threadIdx.x;
  if (t >= nthreads) return;

  const float S = 0.7071067811865476f;  // fp32(1/sqrt(2))
  const int lane = threadIdx.x & 63;

  // 4 contiguous floats, 16B/lane -> fully coalesced.
  float4 r = in[t];
  float v0 = r.x, v1 = r.y, v2 = r.z, v3 = r.w;

  // ---- Analysis ----
  // L1 (lane-local): pairs (v0,v1), (v2,v3)
  float a1_0 = (v0 + v1) * S, d1_0 = (v0 - v1) * S;
  float a1_1 = (v2 + v3) * S, d1_1 = (v2 - v3) * S;
  // L2 (lane-local)
  float a2 = (a1_0 + a1_1) * S, d2 = (a1_0 - a1_1) * S;
  // L3: pair lanes (2j, 2j+1)
  float p1 = __shfl_xor(a2, 1);
  float e3 = (lane & 1) ? p1 : a2;
  float o3 = (lane & 1) ? a2 : p1;
  float a3 = (e3 + o3) * S, d3 = (e3 - o3) * S;  // duplicated across the pair
  // L4: pair lane-pairs (4j..4j+1, 4j+2..4j+3)
  float p2 = __shfl_xor(a3, 2);
  float e4 = (lane & 2) ? p2 : a3;
  float o4 = (lane & 2) ? a3 : p2;
  float a4 = (e4 + o4) * S, d4 = (e4 - o4) * S;  // duplicated across the quad

  // ---- Synthesis (all lane-local) ----
  // L4 inverse: my b3 is even-slot for (lane&2)==0, odd-slot otherwise.
  float b3 = (lane & 2) ? (a4 - d4) * S : (a4 + d4) * S;
  // L3 inverse
  float b2 = (lane & 1) ? (b3 - d3) * S : (b3 + d3) * S;
  // L2 inverse
  float b1_0 = (b2 + d2) * S;
  float b1_1 = (b2 - d2) * S;
  // L1 inverse
  float4 o4v;
  o4v.x = (b1_0 + d1_0) * S;
  o4v.y = (b1_0 - d1_0) * S;
  o4v.z = (b1_1 + d1_1) * S;
  o4v.w = (b1_1 - d1_1) * S;

  out[t] = o4v;
}

extern "C" void kernel_launch(void* const* d_in, const int* in_sizes, int n_in,
                              void* d_out, int out_size, void* d_ws, size_t ws_size,
                              hipStream_t stream) {
  const float* x = (const float*)d_in[0];
  float* out = (float*)d_out;
  int nthreads = out_size / 4;  // 16,777,216
  int block = 256;
  int grid = (nthreads + block - 1) / block;  // 65,536 workgroups
  wavelet_rt_kernel<<<grid, block, 0, stream>>>(
      (const float4*)x, (float4*)out, nthreads);
}